// Round 13
// baseline (96.676 us; speedup 1.0000x reference)
//
#include <hip/hip_runtime.h>
#include <stdint.h>

// CandidateFinder: binary-quantize (x>0), exact match on two 32-bit dim
// groups (union), gather first <=64 matching key indices per query, pad -1.
//
// R12 -> R13: static %8 swizzle had ZERO effect (26us, == R5's no-swizzle
// 25us) -> the assumed blockIdx->XCD mapping is wrong, but the LLC-traffic
// model fits all fused datapoints (nb=64: 128MB redundant raw-key reads
// @ ~5.5TB/s LLC ~= 25us; nb=16: scan-bound 34us). This round: read the
// TRUE XCD via s_getreg(HW_REG_XCC_ID) [HW-verified 0..7 on MI355X] and
// have each block CLAIM a (batch,qblk) slot with atomicCAS in d_ws,
// preferring batch = xcd>>1 -> same-batch blocks share an XCD pair, slab
// fetched once per XCD into its 4MiB L2, redundant reads become L2 hits.
// Claim marker MAGIC != 0xAA poison (same per-replay assumption R9 proved).
// Protocol is mapping-agnostic-correct: 256 slots / 256 blocks pigeonhole;
// an all-256-MAGIC scan is impossible under fresh poison (<=255 claims) so
// it detects stale ws and falls back to blockIdx mapping (also correct).
//
// wave=64 lanes <-> 64 dims: __ballot(v>0) IS the row's two 32-bit group
// signatures in canonical bit order. Matches emitted in ascending key order
// via ballot+popcount prefix = reference's sort-then-truncate.

#define LSEQ 2048
#define DDIM 64
#define KMAX 64
#define QPB  32   // queries per block -> 64 blocks/batch, 256 total at B=4
#define NW   16   // waves per block (1024 threads)
#define GROUP 16  // key rows loaded branch-free per wave per pass
#define MAGIC 0x13572468u
// s_getreg imm: id=20 (HW_REG_XCC_ID, gfx940+), offset=0, size=4
#define XCC_ID_IMM (((4 - 1) << 11) | 20)

__global__ __launch_bounds__(1024) void fused_kernel(
    const float* __restrict__ query, const float* __restrict__ key,
    int* __restrict__ out, unsigned* __restrict__ slots, int use_claim) {
    __shared__ uint2 ks[LSEQ];          // 16 KB: this batch's key signatures
    __shared__ int got_sh;

    const int bpb = LSEQ / QPB;         // 64 blocks per batch
    int lane = threadIdx.x & 63;
    int wave = threadIdx.x >> 6;

    int b, qblk;
    if (use_claim) {
        if (threadIdx.x == 0) {
            int xcd  = __builtin_amdgcn_s_getreg(XCC_ID_IMM) & 7;
            int pref = xcd >> 1;        // batch g lives on XCDs {2g, 2g+1}
            int got = -1, stale_scans = 0;
            while (got < 0) {
                bool saw_free = false;
                for (int pass = 0; pass < 4 && got < 0; ++pass) {
                    int bb = (pref + pass) & 3;
                    unsigned s0 = (blockIdx.x >> 3) & 63;   // spread starts
                    for (int j = 0; j < 64; ++j) {
                        unsigned idx = bb * 64 + ((s0 + j) & 63);
                        unsigned v = __hip_atomic_load(
                            &slots[idx], __ATOMIC_RELAXED,
                            __HIP_MEMORY_SCOPE_AGENT);
                        if (v != MAGIC) {
                            saw_free = true;
                            if (atomicCAS(&slots[idx], v, MAGIC) == v) {
                                got = (int)idx;
                                break;
                            }
                        }
                    }
                }
                if (got < 0 && !saw_free) {
                    // fresh-poison runs can never show 256/256 MAGIC
                    // (<=255 claims exist) -> stale ws: blockIdx mapping
                    if (++stale_scans >= 2) got = (int)blockIdx.x;
                }
            }
            got_sh = got;
        }
        __syncthreads();
        b    = got_sh >> 6;
        qblk = got_sh & 63;
    } else {
        b    = blockIdx.x / bpb;
        qblk = blockIdx.x % bpb;
    }

    // this wave's 2 query signatures first (HBM latency hides under pack)
    const float* qb = query + ((size_t)b * LSEQ + (size_t)qblk * QPB) * DDIM;
    int q0 = wave * 2;                              // local query idx
    float qv0 = qb[(size_t)q0 * DDIM + lane];
    float qv1 = qb[(size_t)(q0 + 1) * DDIM + lane];
    unsigned long long qm0 = __ballot(qv0 > 0.0f);
    unsigned long long qm1 = __ballot(qv1 > 0.0f);

    // ---- pack all 2048 key rows: 128/wave in 8 branch-free groups of 16 ----
    const float* kb = key + (size_t)b * LSEQ * DDIM;
    for (int g = 0; g < LSEQ / (NW * GROUP); ++g) { // 8 groups
        float v[GROUP];
#pragma unroll
        for (int u = 0; u < GROUP; ++u)             // 16 loads, one BB,
            v[u] = kb[(size_t)(g * (NW * GROUP) + u * NW + wave) * DDIM + lane];
        unsigned long long m[GROUP];
#pragma unroll
        for (int u = 0; u < GROUP; ++u)             // branchless (scalar dst)
            m[u] = __ballot(v[u] > 0.0f);
        if (lane == 0) {                            // ONE exec toggle / group
#pragma unroll
            for (int u = 0; u < GROUP; ++u)
                ks[g * (NW * GROUP) + u * NW + wave] =
                    make_uint2((unsigned)m[u], (unsigned)(m[u] >> 32));
        }
    }
    __syncthreads();

    // ---- scan: 2 queries/wave, 16 uint4 LDS loads each (2 keys/lane) ----
    const uint4* kt4 = (const uint4*)ks;
    unsigned long long below = (1ull << lane) - 1ull;
    for (int t = 0; t < 2; ++t) {
        unsigned long long qm = t ? qm1 : qm0;
        unsigned qa = (unsigned)qm, qg = (unsigned)(qm >> 32);
        int* ob = out + ((size_t)b * LSEQ + (size_t)qblk * QPB + q0 + t) * KMAX;

        // fast path: fully branchless, 16 ds_read_b128 back-to-back
        unsigned long long acc = 0;
        int cnt = 0;
#pragma unroll
        for (int i = 0; i < LSEQ / 128; ++i) {      // 16 iters, 128 keys
            uint4 kv = kt4[i * 64 + lane];
            bool mA = (kv.x == qa) | (kv.y == qg);  // key 2*(i*64+lane)
            bool mB = (kv.z == qa) | (kv.w == qg);  // key 2*(i*64+lane)+1
            unsigned long long s;
            s = __ballot(mA); acc |= s; cnt += __popcll(s);
            s = __ballot(mB); acc |= s; cnt += __popcll(s);
        }

        if (acc != 0) {                             // wave-uniform, p~2^-26:
            // exact ordered emit (ascending key idx = sort-then-truncate)
            int c2 = 0;
            for (int c = 0; c < LSEQ / 64; ++c) {
                uint2 kv = ks[c * 64 + lane];
                bool m = (kv.x == qa) || (kv.y == qg);
                unsigned long long mask = __ballot(m);
                if (m) {
                    int pos = c2 + __popcll(mask & below);
                    if (pos < KMAX) ob[pos] = c * 64 + lane;
                }
                c2 += __popcll(mask);
            }
        }
        // pad remaining slots with -1 (64 lanes == KMAX; disjoint vs matches)
        if (lane >= cnt) ob[lane] = -1;
    }
}

extern "C" void kernel_launch(void* const* d_in, const int* in_sizes, int n_in,
                              void* d_out, int out_size, void* d_ws, size_t ws_size,
                              hipStream_t stream) {
    const float* q = (const float*)d_in[0];
    const float* k = (const float*)d_in[1];
    // d_in[2] = head_idx, unused (inputs are already per-head)
    int* out = (int*)d_out;

    int total = in_sizes[0];             // B * L * D
    int B = total / (LSEQ * DDIM);       // = 4

    int grid = B * (LSEQ / QPB);
    unsigned* slots = (unsigned*)d_ws;   // 256 claim slots = 1 KB
    int use_claim = (B == 4 && grid == 256 &&
                     ws_size >= 256 * sizeof(unsigned)) ? 1 : 0;
    fused_kernel<<<grid, 1024, 0, stream>>>(q, k, out, slots, use_claim);
}

// Round 14
// 68.824 us; speedup vs baseline: 1.4047x; 1.4047x over previous
//
#include <hip/hip_runtime.h>
#include <stdint.h>

// CandidateFinder: binary-quantize (x>0), exact match on two 32-bit dim
// groups (union), gather first <=64 matching key indices per query, pad -1.
//
// R13 -> R14: claim protocol cost +18us (CAS storm) — dead. LLC-byte model
// of fused's 25us is suspect (2MB unique working set fits every XCD L2;
// swizzle no-op is consistent with L2 already absorbing bytes). Competing
// model: per-CU ingest ISSUE/latency bound (2048 x 256B row-loads/CU ~=
// 8.7B/cyc). Discriminating test: 4x fewer, 4x wider loads. Lane loads
// float4 (4 dims); wave ingests 4 consecutive rows = 1KB/instr. The 4
// component ballots give row bits in a FIXED within-group permutation
// (bit 8c+s <-> dim 4s+c; s<=7 -> group A, s>=8 -> group B, no mixing),
// assembled per-lane (j=lane&3 handles row r0+j) with 64-bit shifts —
// no shuffles (R3's disease). Queries packed via the IDENTICAL permutation
// (waves 0-7, one float4 load covers 4 queries) -> exact equality
// semantics. Scan/emit unchanged from R12. ONE node, no d_ws.
//
// Matches emitted in ascending key order via ballot+popcount prefix =
// reference's sort-then-truncate.

#define LSEQ 2048
#define DDIM 64
#define KMAX 64
#define QPB  32   // queries per block -> 64 blocks/batch, 256 total at B=4
#define NW   16   // waves per block (1024 threads)

__global__ __launch_bounds__(1024) void fused_kernel(
    const float* __restrict__ query, const float* __restrict__ key,
    int* __restrict__ out) {
    __shared__ uint2 ks[LSEQ];          // 16 KB: key sigs (permuted space)
    __shared__ uint2 qs[QPB];           // this block's query sigs

    const int bpb = LSEQ / QPB;         // 64 blocks per batch
    int b    = blockIdx.x / bpb;
    int qblk = blockIdx.x % bpb;
    int lane = threadIdx.x & 63;
    int wave = threadIdx.x >> 6;
    int j    = lane & 3;                // which of the 4 rows this lane sigs

    const uint4* kb4 = (const uint4*)(key   + (size_t)b * LSEQ * DDIM);
    const uint4* qb4 = (const uint4*)(query + (size_t)b * LSEQ * DDIM);

    // ---- query pack: waves 0-7, one float4 load = 4 query rows each ----
    if (wave < 8) {
        uint4 qv = qb4[((size_t)qblk * QPB + wave * 4) * 16 + lane];
        unsigned long long m0 = __ballot(__uint_as_float(qv.x) > 0.0f);
        unsigned long long m1 = __ballot(__uint_as_float(qv.y) > 0.0f);
        unsigned long long m2 = __ballot(__uint_as_float(qv.z) > 0.0f);
        unsigned long long m3 = __ballot(__uint_as_float(qv.w) > 0.0f);
        unsigned sh = 16u * j;
        unsigned long long t0 = m0 >> sh, t1 = m1 >> sh,
                           t2 = m2 >> sh, t3 = m3 >> sh;
        unsigned sa = (unsigned)(t0 & 0xFF) | ((unsigned)(t1 & 0xFF) << 8)
                    | ((unsigned)(t2 & 0xFF) << 16) | ((unsigned)(t3 & 0xFF) << 24);
        unsigned sb = (unsigned)((t0 >> 8) & 0xFF) | ((unsigned)((t1 >> 8) & 0xFF) << 8)
                    | ((unsigned)((t2 >> 8) & 0xFF) << 16) | ((unsigned)((t3 >> 8) & 0xFF) << 24);
        if (lane < 4) qs[wave * 4 + j] = make_uint2(sa, sb);
    }

    // ---- key pack: 128 rows/wave, 4 groups of 8 branch-free 1KB loads ----
    for (int g = 0; g < 4; ++g) {
        int r0 = wave * 128 + g * 32;               // 32 rows this group
        uint4 kv[8];
#pragma unroll
        for (int i = 0; i < 8; ++i)                 // 8 loads, one BB,
            kv[i] = kb4[(size_t)(r0 + i * 4) * 16 + lane];  // all in flight
        unsigned long long m[8][4];
#pragma unroll
        for (int i = 0; i < 8; ++i) {               // branchless ballots
            m[i][0] = __ballot(__uint_as_float(kv[i].x) > 0.0f);
            m[i][1] = __ballot(__uint_as_float(kv[i].y) > 0.0f);
            m[i][2] = __ballot(__uint_as_float(kv[i].z) > 0.0f);
            m[i][3] = __ballot(__uint_as_float(kv[i].w) > 0.0f);
        }
        unsigned sh = 16u * j;
        uint2 sig[8];
#pragma unroll
        for (int i = 0; i < 8; ++i) {               // per-lane assembly
            unsigned long long t0 = m[i][0] >> sh, t1 = m[i][1] >> sh,
                               t2 = m[i][2] >> sh, t3 = m[i][3] >> sh;
            unsigned sa = (unsigned)(t0 & 0xFF) | ((unsigned)(t1 & 0xFF) << 8)
                        | ((unsigned)(t2 & 0xFF) << 16) | ((unsigned)(t3 & 0xFF) << 24);
            unsigned sb = (unsigned)((t0 >> 8) & 0xFF) | ((unsigned)((t1 >> 8) & 0xFF) << 8)
                        | ((unsigned)((t2 >> 8) & 0xFF) << 16) | ((unsigned)((t3 >> 8) & 0xFF) << 24);
            sig[i] = make_uint2(sa, sb);
        }
        if (lane < 4) {                             // ONE exec toggle / group
#pragma unroll
            for (int i = 0; i < 8; ++i)
                ks[r0 + i * 4 + j] = sig[i];
        }
    }
    __syncthreads();

    // ---- scan: 2 queries/wave, 16 uint4 LDS loads each (2 keys/lane) ----
    const uint4* kt4 = (const uint4*)ks;
    unsigned long long below = (1ull << lane) - 1ull;
    for (int t = 0; t < 2; ++t) {
        uint2 q = qs[wave * 2 + t];                 // uniform addr: broadcast
        unsigned qa = q.x, qg = q.y;
        int* ob = out + ((size_t)b * LSEQ + (size_t)qblk * QPB + wave * 2 + t) * KMAX;

        // fast path: fully branchless, 16 ds_read_b128 back-to-back
        unsigned long long acc = 0;
        int cnt = 0;
#pragma unroll
        for (int i = 0; i < LSEQ / 128; ++i) {      // 16 iters, 128 keys
            uint4 kv = kt4[i * 64 + lane];
            bool mA = (kv.x == qa) | (kv.y == qg);  // key 2*(i*64+lane)
            bool mB = (kv.z == qa) | (kv.w == qg);  // key 2*(i*64+lane)+1
            unsigned long long s;
            s = __ballot(mA); acc |= s; cnt += __popcll(s);
            s = __ballot(mB); acc |= s; cnt += __popcll(s);
        }

        if (acc != 0) {                             // wave-uniform, p~2^-26:
            // exact ordered emit (ascending key idx = sort-then-truncate)
            int c2 = 0;
            for (int c = 0; c < LSEQ / 64; ++c) {
                uint2 kv = ks[c * 64 + lane];
                bool m = (kv.x == qa) || (kv.y == qg);
                unsigned long long mask = __ballot(m);
                if (m) {
                    int pos = c2 + __popcll(mask & below);
                    if (pos < KMAX) ob[pos] = c * 64 + lane;
                }
                c2 += __popcll(mask);
            }
        }
        // pad remaining slots with -1 (64 lanes == KMAX; disjoint vs matches)
        if (lane >= cnt) ob[lane] = -1;
    }
}

extern "C" void kernel_launch(void* const* d_in, const int* in_sizes, int n_in,
                              void* d_out, int out_size, void* d_ws, size_t ws_size,
                              hipStream_t stream) {
    const float* q = (const float*)d_in[0];
    const float* k = (const float*)d_in[1];
    // d_in[2] = head_idx, unused (inputs are already per-head)
    int* out = (int*)d_out;

    int total = in_sizes[0];             // B * L * D
    int B = total / (LSEQ * DDIM);       // = 4

    fused_kernel<<<B * (LSEQ / QPB), 1024, 0, stream>>>(q, k, out);
}